// Round 4
// baseline (746.724 us; speedup 1.0000x reference)
//
#include <hip/hip_runtime.h>
#include <stdint.h>

#define NND 200000   // N nodes; D_IN = D_OUT = 256, B = 256

typedef unsigned short u16;
typedef __attribute__((ext_vector_type(4))) float f4;
typedef __attribute__((ext_vector_type(4))) int   i4;
typedef __attribute__((ext_vector_type(2))) unsigned int u2;
typedef __attribute__((ext_vector_type(8))) short s8;   // 8 bf16 - MFMA A/B frag
typedef __attribute__((ext_vector_type(4))) float acc4; // MFMA C/D frag

__device__ __forceinline__ short f2bf(float f) {
    union { float f; uint32_t u; } v; v.f = f;
    uint32_t r = v.u + 0x7FFFu + ((v.u >> 16) & 1u);   // RNE
    return (short)(r >> 16);
}
__device__ __forceinline__ uint32_t pack2bf(float a, float b) {
    uint32_t ua = __float_as_uint(a), ub = __float_as_uint(b);
    ua = ua + 0x7FFFu + ((ua >> 16) & 1u);
    ub = ub + 0x7FFFu + ((ub >> 16) & 1u);
    return (ua >> 16) | (ub & 0xFFFF0000u);
}
// barrier that does NOT drain vmcnt: LDS consistency only.
__device__ __forceinline__ void bar_lgkm() {
    asm volatile("s_waitcnt lgkmcnt(0)" ::: "memory");
    __builtin_amdgcn_s_barrier();
    asm volatile("" ::: "memory");
}

// ---------------- prep: W fp32 -> bf16 ----------------
__global__ __launch_bounds__(256) void k_prep(const float* __restrict__ Wt,
                                              const float* __restrict__ Wg,
                                              u16* __restrict__ wtb,
                                              u16* __restrict__ wgb) {
    int i = blockIdx.x * 256 + threadIdx.x;   // 256 blocks -> 65536 exactly
    wtb[i] = (u16)f2bf(Wt[i]);
    wgb[i] = (u16)f2bf(Wg[i]);
}

// ---------------- FUSED: partial[bid] = mask[:, nrange] @ h(nodes[nrange]) ----------------
// 256 blocks x 1024 threads (16 waves). Block owns a contiguous 64-node-chunk range
// (53 x 13 + 203 x 12 = 3125 chunks = 200000 nodes). h NEVER touches global memory:
// per chunk it is computed into LDS and immediately consumed by the res-MFMA.
//   P1: stage masks->Ms; h-MFMA (W resident in regs; wave w owns d-slice w*16..);
//       sigmoid epilogue -> Hs [256 d x 64 n bf16, 128B rows, XOR-swz]   | bar
//   P2: res-MFMA (Ms x Hs -> acc[4][4], 256b x 256d f32 per block);
//       stage nodes(c+1)->As; issue nodes(c+2), masks(c+1) reg prefetch  | bar
// No global stores in the loop, no gld16 -> no manual vmcnt anywhere; lgkm-only barriers.
__global__ __launch_bounds__(1024, 2) void k_main(const float* __restrict__ nodes,
                                                  const int* __restrict__ masks,
                                                  const u16* __restrict__ wtb,
                                                  const u16* __restrict__ wgb,
                                                  const float* __restrict__ btp,
                                                  const float* __restrict__ bgp,
                                                  float* __restrict__ partials) {
    __shared__ __align__(16) char smem[98304];
    char* As = smem;           // 32 KB: nodes 64n x 256k bf16, granule-major (32 x 1KB), row-swz
    char* Ms = smem + 32768;   // 32 KB: masks 256b x 64n bf16, 128B rows, XOR-swz
    char* Hs = smem + 65536;   // 32 KB: h    256d x 64n bf16, 128B rows, XOR-swz

    const int tid  = threadIdx.x;
    const int lane = tid & 63, wave = tid >> 6;
    const int quad = lane >> 4, l16 = lane & 15;
    const int dgl  = wave * 16 + l16;          // h-phase: this lane's output d
    const int bh = wave & 3, dq = wave >> 2;   // res-phase: 4x4 wave grid, 64b x 64d

    // ---- W fragments -> registers (once; 2 x 8 x s8 = 64 VGPR) ----
    s8 wT[8], wG[8];
    {
        const u16* wtp = wtb + dgl * 256 + quad * 8;
        const u16* wgp = wgb + dgl * 256 + quad * 8;
#pragma unroll
        for (int ks = 0; ks < 8; ++ks) {
            wT[ks] = *(const s8*)(wtp + ks * 32);
            wG[ks] = *(const s8*)(wgp + ks * 32);
        }
    }
    const float btv = btp[dgl], bgv = bgp[dgl];

    const int bid = blockIdx.x;
    const int NC  = 12 + (bid < 53 ? 1 : 0);
    const int it0 = bid * 12 + min(bid, 53);

    // A staging: 64 rows x 256 k; 16 thr/row, 64B fp32 (-> 32B bf16 = 2 granules) each
    const int arow = tid >> 4, aseg = tid & 15;
    const float* abase = nodes + (size_t)arow * 256 + aseg * 16;
    // M staging: 256 b-rows x 64 n; 4 thr/row, 16 ints each
    const int mr = tid >> 2, seg = tid & 3;
    const size_t mrow = (size_t)mr * NND;
    const int g0 = seg * 2;
    char* msrow = Ms + mr * 128;

    acc4 acc[4][4];
#pragma unroll
    for (int rt = 0; rt < 4; ++rt)
#pragma unroll
        for (int dt = 0; dt < 4; ++dt) acc[rt][dt] = (acc4)0.0f;

    // ---- prologue: nodes(0)+masks(0) -> regs; stage A(0); issue nodes(1) ----
    f4 a0, a1, a2, a3;
    i4 mp[4];
    {
        const int nb = it0 * 64;
        const f4* p = (const f4*)(abase + (size_t)nb * 256);
        a0 = p[0]; a1 = p[1]; a2 = p[2]; a3 = p[3];
        const i4* q = (const i4*)(masks + mrow + nb + seg * 16);
        mp[0] = q[0]; mp[1] = q[1]; mp[2] = q[2]; mp[3] = q[3];
        i4 w0, w1;
        w0.x = (int)pack2bf(a0.x, a0.y); w0.y = (int)pack2bf(a0.z, a0.w);
        w0.z = (int)pack2bf(a1.x, a1.y); w0.w = (int)pack2bf(a1.z, a1.w);
        w1.x = (int)pack2bf(a2.x, a2.y); w1.y = (int)pack2bf(a2.z, a2.w);
        w1.z = (int)pack2bf(a3.x, a3.y); w1.w = (int)pack2bf(a3.z, a3.w);
        const int ga = aseg * 2, gb = ga + 1;
        *(i4*)(As + ga * 1024 + (((arow & 56) | ((arow ^ ga) & 7)) << 4)) = w0;
        *(i4*)(As + gb * 1024 + (((arow & 56) | ((arow ^ gb) & 7)) << 4)) = w1;
        const f4* p1 = (const f4*)(abase + (size_t)(nb + 64) * 256);
        a0 = p1[0]; a1 = p1[1]; a2 = p1[2]; a3 = p1[3];
    }
    bar_lgkm();

    for (int c = 0; c < NC; ++c) {
        const int nb = (it0 + c) * 64;
        // ---- P1: stage M(c) (regs loaded a chunk ago) ----
        {
            uint32_t w0 = (((uint32_t)(-mp[0].x)) & 0x3F80u) | ((((uint32_t)(-mp[0].y)) & 0x3F80u) << 16);
            uint32_t w1 = (((uint32_t)(-mp[0].z)) & 0x3F80u) | ((((uint32_t)(-mp[0].w)) & 0x3F80u) << 16);
            uint32_t w2 = (((uint32_t)(-mp[1].x)) & 0x3F80u) | ((((uint32_t)(-mp[1].y)) & 0x3F80u) << 16);
            uint32_t w3 = (((uint32_t)(-mp[1].z)) & 0x3F80u) | ((((uint32_t)(-mp[1].w)) & 0x3F80u) << 16);
            uint32_t w4 = (((uint32_t)(-mp[2].x)) & 0x3F80u) | ((((uint32_t)(-mp[2].y)) & 0x3F80u) << 16);
            uint32_t w5 = (((uint32_t)(-mp[2].z)) & 0x3F80u) | ((((uint32_t)(-mp[2].w)) & 0x3F80u) << 16);
            uint32_t w6 = (((uint32_t)(-mp[3].x)) & 0x3F80u) | ((((uint32_t)(-mp[3].y)) & 0x3F80u) << 16);
            uint32_t w7 = (((uint32_t)(-mp[3].z)) & 0x3F80u) | ((((uint32_t)(-mp[3].w)) & 0x3F80u) << 16);
            i4 ma, mb;
            ma.x = (int)w0; ma.y = (int)w1; ma.z = (int)w2; ma.w = (int)w3;
            mb.x = (int)w4; mb.y = (int)w5; mb.z = (int)w6; mb.w = (int)w7;
            *(i4*)(msrow + (((g0    ) ^ (mr & 7)) << 4)) = ma;
            *(i4*)(msrow + (((g0 + 1) ^ (mr & 7)) << 4)) = mb;
        }
        // issue masks(c+1) (consumed next P1 -> full chunk of latency cover)
        if (c + 1 < NC) {
            const i4* q = (const i4*)(masks + mrow + (nb + 64) + seg * 16);
            mp[0] = q[0]; mp[1] = q[1]; mp[2] = q[2]; mp[3] = q[3];
        }
        // ---- h-MFMA: 64 n x 16 d x K=256, both matrices (64 MFMA/wave) ----
        acc4 at_[4], ag_[4];
#pragma unroll
        for (int rt = 0; rt < 4; ++rt) { at_[rt] = (acc4)0.0f; ag_[rt] = (acc4)0.0f; }
#pragma unroll
        for (int ks = 0; ks < 8; ++ks) {
            const int kq = ks * 4 + quad;
#pragma unroll
            for (int rt = 0; rt < 4; ++rt) {
                const int row = rt * 16 + l16;
                s8 af = *(const s8*)(As + kq * 1024 + (((row & 56) | ((row ^ kq) & 7)) << 4));
                at_[rt] = __builtin_amdgcn_mfma_f32_16x16x32_bf16(af, wT[ks], at_[rt], 0, 0, 0);
                ag_[rt] = __builtin_amdgcn_mfma_f32_16x16x32_bf16(af, wG[ks], ag_[rt], 0, 0, 0);
            }
        }
        // ---- epilogue: h = (data+bt)*sigmoid(gate+bg) -> bf16 -> Hs[d][n] ----
#pragma unroll
        for (int rt = 0; rt < 4; ++rt) {
            float h0 = (at_[rt][0] + btv) / (1.0f + __expf(-(ag_[rt][0] + bgv)));
            float h1 = (at_[rt][1] + btv) / (1.0f + __expf(-(ag_[rt][1] + bgv)));
            float h2 = (at_[rt][2] + btv) / (1.0f + __expf(-(ag_[rt][2] + bgv)));
            float h3 = (at_[rt][3] + btv) / (1.0f + __expf(-(ag_[rt][3] + bgv)));
            u2 pk; pk.x = pack2bf(h0, h1); pk.y = pack2bf(h2, h3);
            const int g = rt * 2 + (quad >> 1);          // n-granule (n = rt*16 + quad*4)
            *(u2*)(Hs + dgl * 128 + ((g ^ (dgl & 7)) << 4) + (quad & 1) * 8) = pk;
        }
        bar_lgkm();
        // ---- P2: res-MFMA: 256b x 256d x K=64 (32 MFMA/wave) ----
#pragma unroll
        for (int ks = 0; ks < 2; ++ks) {
            const int q = (ks << 2) | quad;
            s8 af[4];
#pragma unroll
            for (int rt = 0; rt < 4; ++rt) {
                const int r = bh * 64 + rt * 16 + l16;
                af[rt] = *(const s8*)(Ms + r * 128 + ((q ^ (r & 7)) << 4));
            }
#pragma unroll
            for (int dt = 0; dt < 4; ++dt) {
                const int dl = dq * 64 + dt * 16 + l16;
                s8 bf_ = *(const s8*)(Hs + dl * 128 + ((q ^ (dl & 7)) << 4));
#pragma unroll
                for (int rt = 0; rt < 4; ++rt)
                    acc[rt][dt] = __builtin_amdgcn_mfma_f32_16x16x32_bf16(af[rt], bf_, acc[rt][dt], 0, 0, 0);
            }
        }
        // ---- stage A(c+1) (regs); issue nodes(c+2) ----
        if (c + 1 < NC) {
            i4 w0, w1;
            w0.x = (int)pack2bf(a0.x, a0.y); w0.y = (int)pack2bf(a0.z, a0.w);
            w0.z = (int)pack2bf(a1.x, a1.y); w0.w = (int)pack2bf(a1.z, a1.w);
            w1.x = (int)pack2bf(a2.x, a2.y); w1.y = (int)pack2bf(a2.z, a2.w);
            w1.z = (int)pack2bf(a3.x, a3.y); w1.w = (int)pack2bf(a3.z, a3.w);
            const int ga = aseg * 2, gb = ga + 1;
            *(i4*)(As + ga * 1024 + (((arow & 56) | ((arow ^ ga) & 7)) << 4)) = w0;
            *(i4*)(As + gb * 1024 + (((arow & 56) | ((arow ^ gb) & 7)) << 4)) = w1;
            if (c + 2 < NC) {
                const f4* p = (const f4*)(abase + (size_t)(nb + 128) * 256);
                a0 = p[0]; a1 = p[1]; a2 = p[2]; a3 = p[3];
            }
        }
        bar_lgkm();
    }
    // ---- epilogue: plain f32 partial store ----
    float* pb = partials + (size_t)bid * 65536;
#pragma unroll
    for (int rt = 0; rt < 4; ++rt)
#pragma unroll
        for (int dt = 0; dt < 4; ++dt) {
            const int b = bh * 64 + rt * 16 + quad * 4;
            const int d = dq * 64 + dt * 16 + l16;
#pragma unroll
            for (int r = 0; r < 4; ++r)
                pb[(size_t)(b + r) * 256 + d] = acc[rt][dt][r];
        }
}

// ---------------- reduce: out[b][d] = sum_bid partials[bid][b][d] ----------------
__global__ __launch_bounds__(1024) void k_red(const float* __restrict__ partials,
                                              float* __restrict__ outp) {
    __shared__ float red[4][256];
    const int b = blockIdx.x;
    const int d = threadIdx.x & 255, ks = threadIdx.x >> 8;
    const float* p = partials + (size_t)(ks * 64) * 65536 + b * 256 + d;
    float s0 = 0.f, s1 = 0.f, s2 = 0.f, s3 = 0.f;
#pragma unroll 4
    for (int j = 0; j < 64; j += 4) {
        s0 += p[(size_t)(j + 0) * 65536];
        s1 += p[(size_t)(j + 1) * 65536];
        s2 += p[(size_t)(j + 2) * 65536];
        s3 += p[(size_t)(j + 3) * 65536];
    }
    red[ks][d] = (s0 + s1) + (s2 + s3);
    __syncthreads();
    if (ks == 0)
        outp[b * 256 + d] = (red[0][d] + red[1][d]) + (red[2][d] + red[3][d]);
}

extern "C" void kernel_launch(void* const* d_in, const int* in_sizes, int n_in,
                              void* d_out, int out_size, void* d_ws, size_t ws_size,
                              hipStream_t stream) {
    const float* nodes = (const float*)d_in[0];
    const int*   masks = (const int*)d_in[1];
    const float* Wt    = (const float*)d_in[2];
    const float* bt    = (const float*)d_in[3];
    const float* Wg    = (const float*)d_in[4];
    const float* bg    = (const float*)d_in[5];
    float* outp = (float*)d_out;

    // ws layout: wtb/wgb bf16 (131,072 B); partials f32 [256][256][256] = 67,108,864 B
    u16*   wtb  = (u16*)d_ws;
    u16*   wgb  = wtb + 65536;
    float* part = (float*)((char*)d_ws + 262144);

    k_prep<<<dim3(256), dim3(256), 0, stream>>>(Wt, Wg, wtb, wgb);
    k_main<<<dim3(256), dim3(1024), 0, stream>>>(nodes, masks, wtb, wgb, bt, bg, part);
    k_red<<<dim3(256), dim3(1024), 0, stream>>>(part, outp);
}

// Round 5
// 698.373 us; speedup vs baseline: 1.0692x; 1.0692x over previous
//
#include <hip/hip_runtime.h>
#include <stdint.h>

#define NND 200000   // N nodes; D_IN = D_OUT = 256, B = 256

typedef unsigned short u16;
typedef __attribute__((ext_vector_type(4))) float f4;
typedef __attribute__((ext_vector_type(4))) int   i4;
typedef __attribute__((ext_vector_type(2))) unsigned int u2;
typedef __attribute__((ext_vector_type(8))) short s8;   // 8 bf16 - MFMA A/B frag
typedef __attribute__((ext_vector_type(4))) float acc4; // MFMA C/D frag

__device__ __forceinline__ short f2bf(float f) {
    union { float f; uint32_t u; } v; v.f = f;
    uint32_t r = v.u + 0x7FFFu + ((v.u >> 16) & 1u);   // RNE
    return (short)(r >> 16);
}
__device__ __forceinline__ uint32_t pack2bf(float a, float b) {
    uint32_t ua = __float_as_uint(a), ub = __float_as_uint(b);
    ua = ua + 0x7FFFu + ((ua >> 16) & 1u);
    ub = ub + 0x7FFFu + ((ub >> 16) & 1u);
    return (ua >> 16) | (ub & 0xFFFF0000u);
}
// barrier that does NOT drain vmcnt: LDS consistency only.
__device__ __forceinline__ void bar_lgkm() {
    asm volatile("s_waitcnt lgkmcnt(0)" ::: "memory");
    __builtin_amdgcn_s_barrier();
    asm volatile("" ::: "memory");
}
__device__ __forceinline__ i4 mask2bf(i4 m0, i4 m1) {   // 8 x {0,1} int -> 8 bf16
    i4 w;
    w.x = (int)(((uint32_t)(-m0.x) & 0x3F80u) | (((uint32_t)(-m0.y) & 0x3F80u) << 16));
    w.y = (int)(((uint32_t)(-m0.z) & 0x3F80u) | (((uint32_t)(-m0.w) & 0x3F80u) << 16));
    w.z = (int)(((uint32_t)(-m1.x) & 0x3F80u) | (((uint32_t)(-m1.y) & 0x3F80u) << 16));
    w.w = (int)(((uint32_t)(-m1.z) & 0x3F80u) | (((uint32_t)(-m1.w) & 0x3F80u) << 16));
    return w;
}

// ---------------- prep: W fp32 -> bf16 ----------------
__global__ __launch_bounds__(256) void k_prep(const float* __restrict__ Wt,
                                              const float* __restrict__ Wg,
                                              u16* __restrict__ wtb,
                                              u16* __restrict__ wgb) {
    int i = blockIdx.x * 256 + threadIdx.x;   // 256 blocks -> 65536 exactly
    wtb[i] = (u16)f2bf(Wt[i]);
    wgb[i] = (u16)f2bf(Wg[i]);
}

// ---------------- FUSED: partial[half][xr] = mask[half-b, nrange] @ h(nodes[nrange]) --------
// 512 blocks = dim3(2 b-halves FAST, 256 n-ranges) x 512 threads (8 waves).
// __launch_bounds__(512,1): 1 block/CU = 2 waves/SIMD -> 256-VGPR budget (fixes R4 spill).
// Register plan (~244 peak): W resident 128 (wave owns 32 d) + res acc 64 (128b x 256d / 8
// waves = 64b x 64d each) + h acc 16 (dt-sequential) + node pf 16 + mask pf 8 + temps.
// Chunk = 32 n. Per chunk: h-MFMA(As->Hs, sigmoid fused) | bar | res-MFMA(Ms x Hs -> acc)
// | bar. Nodes+masks reg-prefetched 1 chunk ahead; 2 lgkm-only barriers; no loop stores.
// b-half pair (0,y),(1,y) dispatch adjacently -> 2nd block's node reads are L3 hits.
__global__ __launch_bounds__(512, 1) void k_main(const float* __restrict__ nodes,
                                                 const int* __restrict__ masks,
                                                 const u16* __restrict__ wtb,
                                                 const u16* __restrict__ wgb,
                                                 const float* __restrict__ btp,
                                                 const float* __restrict__ bgp,
                                                 float* __restrict__ partials) {
    __shared__ __align__(16) char smem[65536];
    char* As0 = smem;           // 2 x 16384: nodes 32n x 256k bf16, granule g=k>>3: g*512+slot(row,g)*16
    char* Ms0 = smem + 32768;   // 2 x 8192: masks 128b x 32n bf16, row*64 + ((g^ (row&3))<<4)
    char* Hs  = smem + 49152;   // 16384: h 256d x 32n bf16, row*64 + ((g ^ (row&3))<<4)

    const int tid  = threadIdx.x;
    const int lane = tid & 63, wave = tid >> 6;
    const int quad = lane >> 4, l16 = lane & 15;

    const int half = blockIdx.x;            // b-half (fast grid dim)
    const int xr   = blockIdx.y;            // n-range
    const int NC   = (xr < 106) ? 25 : 24;  // 106*25 + 150*24 = 6250 chunks x 32 n = 200000
    const int ch0  = (xr < 106) ? xr * 25 : 2650 + (xr - 106) * 24;
    const int b0   = half * 128;

    // ---- W resident: wave owns d in [wave*32, wave*32+32) ----
    const int d0 = wave * 32 + l16, d1 = d0 + 16;
    s8 wT0[8], wT1[8], wG0[8], wG1[8];
    {
        const u16* t0p = wtb + d0 * 256 + quad * 8;
        const u16* t1p = wtb + d1 * 256 + quad * 8;
        const u16* g0p = wgb + d0 * 256 + quad * 8;
        const u16* g1p = wgb + d1 * 256 + quad * 8;
#pragma unroll
        for (int ks = 0; ks < 8; ++ks) {
            wT0[ks] = *(const s8*)(t0p + ks * 32);
            wT1[ks] = *(const s8*)(t1p + ks * 32);
            wG0[ks] = *(const s8*)(g0p + ks * 32);
            wG1[ks] = *(const s8*)(g1p + ks * 32);
        }
    }
    const float bt0 = btp[d0], bt1 = btp[d1];
    const float bg0 = bgp[d0], bg1 = bgp[d1];

    // res wave tile: 2(b) x 4(d) wave grid
    const int bh = wave >> 2, dq = wave & 3;

    // node staging map: 32 rows x 16 segs x 64B fp32 -> 2 bf16 granules
    const int arow = tid >> 4, akseg = tid & 15;
    const float* abase = nodes + (size_t)arow * 256 + akseg * 16;
    const int ag0 = akseg * 2;
    const int aw0 = ag0 * 512 + (((arow & 24) | ((arow ^ ag0) & 7)) << 4);
    const int aw1 = (ag0 + 1) * 512 + (((arow & 24) | ((arow ^ (ag0 + 1)) & 7)) << 4);
    // mask staging map: 128 rows x 4 granules x 8n
    const int mr = tid >> 2, gm = tid & 3;
    const int* mbase = masks + (size_t)(b0 + mr) * NND + gm * 8;
    const int mwoff = mr * 64 + ((gm ^ (mr & 3)) << 4);

    acc4 acc[4][4];
#pragma unroll
    for (int rt = 0; rt < 4; ++rt)
#pragma unroll
        for (int dt = 0; dt < 4; ++dt) acc[rt][dt] = (acc4)0.0f;

    f4 a0, a1, a2, a3;
    i4 mp0, mp1;

    // ---- prologue: chunk 0 -> LDS; issue chunk 1 -> regs ----
    {
        const int nb = ch0 * 32;
        const f4* p = (const f4*)(abase + (size_t)nb * 256);
        a0 = p[0]; a1 = p[1]; a2 = p[2]; a3 = p[3];
        const i4* q = (const i4*)(mbase + nb);
        mp0 = q[0]; mp1 = q[1];
        i4 w0, w1;
        w0.x = (int)pack2bf(a0.x, a0.y); w0.y = (int)pack2bf(a0.z, a0.w);
        w0.z = (int)pack2bf(a1.x, a1.y); w0.w = (int)pack2bf(a1.z, a1.w);
        w1.x = (int)pack2bf(a2.x, a2.y); w1.y = (int)pack2bf(a2.z, a2.w);
        w1.z = (int)pack2bf(a3.x, a3.y); w1.w = (int)pack2bf(a3.z, a3.w);
        *(i4*)(As0 + aw0) = w0;
        *(i4*)(As0 + aw1) = w1;
        *(i4*)(Ms0 + mwoff) = mask2bf(mp0, mp1);
        if (NC > 1) {
            const f4* p1 = (const f4*)(abase + (size_t)(nb + 32) * 256);
            a0 = p1[0]; a1 = p1[1]; a2 = p1[2]; a3 = p1[3];
            const i4* q1 = (const i4*)(mbase + nb + 32);
            mp0 = q1[0]; mp1 = q1[1];
        }
    }
    bar_lgkm();

    int cur = 0;
    for (int c = 0; c < NC; ++c) {
        const char* Ar = As0 + cur * 16384;
        // ---- B+C: h-MFMA + fused sigmoid epilogue, dt-sequential (h acc = 16 regs) ----
        {   // dt = 0
            acc4 t0 = (acc4)0.f, t1 = (acc4)0.f, ga = (acc4)0.f, gb = (acc4)0.f;
#pragma unroll
            for (int ks = 0; ks < 8; ++ks) {
                const int gg = ks * 4 + quad;
                const int ab = gg * 512 + (((l16 & 8) | ((l16 ^ gg) & 7)) << 4);
                s8 af0 = *(const s8*)(Ar + ab);
                s8 af1 = *(const s8*)(Ar + ab + 256);
                t0 = __builtin_amdgcn_mfma_f32_16x16x32_bf16(af0, wT0[ks], t0, 0, 0, 0);
                ga = __builtin_amdgcn_mfma_f32_16x16x32_bf16(af0, wG0[ks], ga, 0, 0, 0);
                t1 = __builtin_amdgcn_mfma_f32_16x16x32_bf16(af1, wT0[ks], t1, 0, 0, 0);
                gb = __builtin_amdgcn_mfma_f32_16x16x32_bf16(af1, wG0[ks], gb, 0, 0, 0);
            }
#pragma unroll
            for (int nt = 0; nt < 2; ++nt) {
                const acc4 t = nt ? t1 : t0;
                const acc4 g = nt ? gb : ga;
                float h0 = (t[0] + bt0) / (1.0f + __expf(-(g[0] + bg0)));
                float h1 = (t[1] + bt0) / (1.0f + __expf(-(g[1] + bg0)));
                float h2 = (t[2] + bt0) / (1.0f + __expf(-(g[2] + bg0)));
                float h3 = (t[3] + bt0) / (1.0f + __expf(-(g[3] + bg0)));
                u2 pk; pk.x = pack2bf(h0, h1); pk.y = pack2bf(h2, h3);
                const int gn = nt * 2 + (quad >> 1);
                *(u2*)(Hs + d0 * 64 + ((gn ^ (d0 & 3)) << 4) + (quad & 1) * 8) = pk;
            }
        }
        {   // dt = 1
            acc4 t0 = (acc4)0.f, t1 = (acc4)0.f, ga = (acc4)0.f, gb = (acc4)0.f;
#pragma unroll
            for (int ks = 0; ks < 8; ++ks) {
                const int gg = ks * 4 + quad;
                const int ab = gg * 512 + (((l16 & 8) | ((l16 ^ gg) & 7)) << 4);
                s8 af0 = *(const s8*)(Ar + ab);
                s8 af1 = *(const s8*)(Ar + ab + 256);
                t0 = __builtin_amdgcn_mfma_f32_16x16x32_bf16(af0, wT1[ks], t0, 0, 0, 0);
                ga = __builtin_amdgcn_mfma_f32_16x16x32_bf16(af0, wG1[ks], ga, 0, 0, 0);
                t1 = __builtin_amdgcn_mfma_f32_16x16x32_bf16(af1, wT1[ks], t1, 0, 0, 0);
                gb = __builtin_amdgcn_mfma_f32_16x16x32_bf16(af1, wG1[ks], gb, 0, 0, 0);
            }
#pragma unroll
            for (int nt = 0; nt < 2; ++nt) {
                const acc4 t = nt ? t1 : t0;
                const acc4 g = nt ? gb : ga;
                float h0 = (t[0] + bt1) / (1.0f + __expf(-(g[0] + bg1)));
                float h1 = (t[1] + bt1) / (1.0f + __expf(-(g[1] + bg1)));
                float h2 = (t[2] + bt1) / (1.0f + __expf(-(g[2] + bg1)));
                float h3 = (t[3] + bt1) / (1.0f + __expf(-(g[3] + bg1)));
                u2 pk; pk.x = pack2bf(h0, h1); pk.y = pack2bf(h2, h3);
                const int gn = nt * 2 + (quad >> 1);
                *(u2*)(Hs + d1 * 64 + ((gn ^ (d1 & 3)) << 4) + (quad & 1) * 8) = pk;
            }
        }
        // ---- D: stage chunk c+1 (regs, loaded a chunk ago; compiler waits vmcnt here) ----
        if (c + 1 < NC) {
            char* Aw = As0 + (cur ^ 1) * 16384;
            i4 w0, w1;
            w0.x = (int)pack2bf(a0.x, a0.y); w0.y = (int)pack2bf(a0.z, a0.w);
            w0.z = (int)pack2bf(a1.x, a1.y); w0.w = (int)pack2bf(a1.z, a1.w);
            w1.x = (int)pack2bf(a2.x, a2.y); w1.y = (int)pack2bf(a2.z, a2.w);
            w1.z = (int)pack2bf(a3.x, a3.y); w1.w = (int)pack2bf(a3.z, a3.w);
            *(i4*)(Aw + aw0) = w0;
            *(i4*)(Aw + aw1) = w1;
            *(i4*)(Ms0 + (cur ^ 1) * 8192 + mwoff) = mask2bf(mp0, mp1);
        }
        // ---- E: issue chunk c+2 loads (stay in flight across lgkm-only barriers) ----
        if (c + 2 < NC) {
            const int nb2 = (ch0 + c + 2) * 32;
            const f4* p = (const f4*)(abase + (size_t)nb2 * 256);
            a0 = p[0]; a1 = p[1]; a2 = p[2]; a3 = p[3];
            const i4* q = (const i4*)(mbase + nb2);
            mp0 = q[0]; mp1 = q[1];
        }
        bar_lgkm();   // F: Hs + As/Ms[cur^1] visible
        // ---- G: res-MFMA: 128b x 256d x K=32 (16 MFMA/wave) ----
        {
            const char* Mr = Ms0 + cur * 8192;
            s8 maf[4];
#pragma unroll
            for (int rt = 0; rt < 4; ++rt) {
                const int r = bh * 64 + rt * 16 + l16;
                maf[rt] = *(const s8*)(Mr + r * 64 + ((quad ^ (r & 3)) << 4));
            }
#pragma unroll
            for (int dt = 0; dt < 4; ++dt) {
                const int dl = dq * 64 + dt * 16 + l16;
                s8 hb = *(const s8*)(Hs + dl * 64 + ((quad ^ (dl & 3)) << 4));
#pragma unroll
                for (int rt = 0; rt < 4; ++rt)
                    acc[rt][dt] = __builtin_amdgcn_mfma_f32_16x16x32_bf16(maf[rt], hb, acc[rt][dt], 0, 0, 0);
            }
        }
        bar_lgkm();   // H: res reads of Hs/Ms[cur] done
        cur ^= 1;
    }
    // ---- epilogue: f32 partial store ----
    float* pb = partials + (((size_t)half * 256 + xr) << 15);
#pragma unroll
    for (int rt = 0; rt < 4; ++rt)
#pragma unroll
        for (int dt = 0; dt < 4; ++dt) {
            const int b = bh * 64 + rt * 16 + quad * 4;
            const int d = dq * 64 + dt * 16 + l16;
#pragma unroll
            for (int r = 0; r < 4; ++r)
                pb[(size_t)(b + r) * 256 + d] = acc[rt][dt][r];
        }
}

// ---------------- reduce: out[b][d] = sum_xr partials[b>>7][xr][b&127][d] ----------------
__global__ __launch_bounds__(1024) void k_red(const float* __restrict__ partials,
                                              float* __restrict__ outp) {
    __shared__ float red[4][256];
    const int b = blockIdx.x;
    const int d = threadIdx.x & 255, ks = threadIdx.x >> 8;
    const int half = b >> 7, lb = b & 127;
    const float* p = partials + (((size_t)half * 256 + ks * 64) << 15) + lb * 256 + d;
    float s0 = 0.f, s1 = 0.f, s2 = 0.f, s3 = 0.f;
#pragma unroll 4
    for (int j = 0; j < 64; j += 4) {
        s0 += p[(size_t)(j + 0) << 15];
        s1 += p[(size_t)(j + 1) << 15];
        s2 += p[(size_t)(j + 2) << 15];
        s3 += p[(size_t)(j + 3) << 15];
    }
    red[ks][d] = (s0 + s1) + (s2 + s3);
    __syncthreads();
    if (ks == 0)
        outp[b * 256 + d] = (red[0][d] + red[1][d]) + (red[2][d] + red[3][d]);
}

extern "C" void kernel_launch(void* const* d_in, const int* in_sizes, int n_in,
                              void* d_out, int out_size, void* d_ws, size_t ws_size,
                              hipStream_t stream) {
    const float* nodes = (const float*)d_in[0];
    const int*   masks = (const int*)d_in[1];
    const float* Wt    = (const float*)d_in[2];
    const float* bt    = (const float*)d_in[3];
    const float* Wg    = (const float*)d_in[4];
    const float* bg    = (const float*)d_in[5];
    float* outp = (float*)d_out;

    // ws layout: wtb/wgb bf16 (131,072 B); partials f32 [2][256][128][256] = 67,108,864 B
    u16*   wtb  = (u16*)d_ws;
    u16*   wgb  = wtb + 65536;
    float* part = (float*)((char*)d_ws + 262144);

    k_prep<<<dim3(256), dim3(256), 0, stream>>>(Wt, Wg, wtb, wgb);
    k_main<<<dim3(2, 256), dim3(512), 0, stream>>>(nodes, masks, wtb, wgb, bt, bg, part);
    k_red<<<dim3(256), dim3(1024), 0, stream>>>(part, outp);
}

// Round 6
// 697.660 us; speedup vs baseline: 1.0703x; 1.0010x over previous
//
#include <hip/hip_runtime.h>
#include <stdint.h>

#define NND 200000   // N nodes; D_IN = D_OUT = 256, B = 256

typedef unsigned short u16;
typedef __attribute__((ext_vector_type(4))) float f4;
typedef __attribute__((ext_vector_type(4))) int   i4;
typedef __attribute__((ext_vector_type(2))) unsigned int u2;
typedef __attribute__((ext_vector_type(8))) short s8;   // 8 bf16 - MFMA A/B frag
typedef __attribute__((ext_vector_type(4))) float acc4; // MFMA C/D frag

__device__ __forceinline__ short f2bf(float f) {
    union { float f; uint32_t u; } v; v.f = f;
    uint32_t r = v.u + 0x7FFFu + ((v.u >> 16) & 1u);   // RNE
    return (short)(r >> 16);
}
__device__ __forceinline__ uint32_t pack2bf(float a, float b) {
    uint32_t ua = __float_as_uint(a), ub = __float_as_uint(b);
    ua = ua + 0x7FFFu + ((ua >> 16) & 1u);
    ub = ub + 0x7FFFu + ((ub >> 16) & 1u);
    return (ua >> 16) | (ub & 0xFFFF0000u);
}
// barrier that does NOT drain vmcnt: LDS consistency only.
__device__ __forceinline__ void bar_lgkm() {
    asm volatile("s_waitcnt lgkmcnt(0)" ::: "memory");
    __builtin_amdgcn_s_barrier();
    asm volatile("" ::: "memory");
}
__device__ __forceinline__ i4 mask2bf(i4 m0, i4 m1) {   // 8 x {0,1} int -> 8 bf16
    i4 w;
    w.x = (int)(((uint32_t)(-m0.x) & 0x3F80u) | (((uint32_t)(-m0.y) & 0x3F80u) << 16));
    w.y = (int)(((uint32_t)(-m0.z) & 0x3F80u) | (((uint32_t)(-m0.w) & 0x3F80u) << 16));
    w.z = (int)(((uint32_t)(-m1.x) & 0x3F80u) | (((uint32_t)(-m1.y) & 0x3F80u) << 16));
    w.w = (int)(((uint32_t)(-m1.z) & 0x3F80u) | (((uint32_t)(-m1.w) & 0x3F80u) << 16));
    return w;
}

// ---------------- prep: W fp32 -> bf16 ----------------
__global__ __launch_bounds__(256) void k_prep(const float* __restrict__ Wt,
                                              const float* __restrict__ Wg,
                                              u16* __restrict__ wtb,
                                              u16* __restrict__ wgb) {
    int i = blockIdx.x * 256 + threadIdx.x;   // 256 blocks -> 65536 exactly
    wtb[i] = (u16)f2bf(Wt[i]);
    wgb[i] = (u16)f2bf(Wg[i]);
}

// ---------------- FUSED: partial[half][xr] = mask[half-b, nrange] @ h(nodes[nrange]) --------
// Identical structure to R5. ONE change: amdgpu_waves_per_eu(1,2) forces the register
// allocator to stop targeting 4 waves/SIMD (128-reg cap -> ~115 spilled regs/lane, the
// R5 424us disaster: +34MB spill WRITE, scratch-reload chains gating every MFMA group).
// With max=2 waves/EU the allocator may use up to 256 VGPRs; demand ~244 -> zero spill,
// W genuinely register-resident for the first time.
__global__ __launch_bounds__(512)
__attribute__((amdgpu_waves_per_eu(1, 2)))
void k_main(const float* __restrict__ nodes,
            const int* __restrict__ masks,
            const u16* __restrict__ wtb,
            const u16* __restrict__ wgb,
            const float* __restrict__ btp,
            const float* __restrict__ bgp,
            float* __restrict__ partials) {
    __shared__ __align__(16) char smem[65536];
    char* As0 = smem;           // 2 x 16384: nodes 32n x 256k bf16, granule g=k>>3: g*512+slot(row,g)*16
    char* Ms0 = smem + 32768;   // 2 x 8192: masks 128b x 32n bf16, row*64 + ((g^(row&3))<<4)
    char* Hs  = smem + 49152;   // 16384: h 256d x 32n bf16, row*64 + ((g ^ (row&3))<<4)

    const int tid  = threadIdx.x;
    const int lane = tid & 63, wave = tid >> 6;
    const int quad = lane >> 4, l16 = lane & 15;

    const int half = blockIdx.x;            // b-half (fast grid dim)
    const int xr   = blockIdx.y;            // n-range
    const int NC   = (xr < 106) ? 25 : 24;  // 106*25 + 150*24 = 6250 chunks x 32 n = 200000
    const int ch0  = (xr < 106) ? xr * 25 : 2650 + (xr - 106) * 24;
    const int b0   = half * 128;

    // ---- W resident: wave owns d in [wave*32, wave*32+32) ----
    const int d0 = wave * 32 + l16, d1 = d0 + 16;
    s8 wT0[8], wT1[8], wG0[8], wG1[8];
    {
        const u16* t0p = wtb + d0 * 256 + quad * 8;
        const u16* t1p = wtb + d1 * 256 + quad * 8;
        const u16* g0p = wgb + d0 * 256 + quad * 8;
        const u16* g1p = wgb + d1 * 256 + quad * 8;
#pragma unroll
        for (int ks = 0; ks < 8; ++ks) {
            wT0[ks] = *(const s8*)(t0p + ks * 32);
            wT1[ks] = *(const s8*)(t1p + ks * 32);
            wG0[ks] = *(const s8*)(g0p + ks * 32);
            wG1[ks] = *(const s8*)(g1p + ks * 32);
        }
    }
    const float bt0 = btp[d0], bt1 = btp[d1];
    const float bg0 = bgp[d0], bg1 = bgp[d1];

    // res wave tile: 2(b) x 4(d) wave grid
    const int bh = wave >> 2, dq = wave & 3;

    // node staging map: 32 rows x 16 segs x 64B fp32 -> 2 bf16 granules
    const int arow = tid >> 4, akseg = tid & 15;
    const float* abase = nodes + (size_t)arow * 256 + akseg * 16;
    const int ag0 = akseg * 2;
    const int aw0 = ag0 * 512 + (((arow & 24) | ((arow ^ ag0) & 7)) << 4);
    const int aw1 = (ag0 + 1) * 512 + (((arow & 24) | ((arow ^ (ag0 + 1)) & 7)) << 4);
    // mask staging map: 128 rows x 4 granules x 8n
    const int mr = tid >> 2, gm = tid & 3;
    const int* mbase = masks + (size_t)(b0 + mr) * NND + gm * 8;
    const int mwoff = mr * 64 + ((gm ^ (mr & 3)) << 4);

    acc4 acc[4][4];
#pragma unroll
    for (int rt = 0; rt < 4; ++rt)
#pragma unroll
        for (int dt = 0; dt < 4; ++dt) acc[rt][dt] = (acc4)0.0f;

    f4 a0, a1, a2, a3;
    i4 mp0, mp1;

    // ---- prologue: chunk 0 -> LDS; issue chunk 1 -> regs ----
    {
        const int nb = ch0 * 32;
        const f4* p = (const f4*)(abase + (size_t)nb * 256);
        a0 = p[0]; a1 = p[1]; a2 = p[2]; a3 = p[3];
        const i4* q = (const i4*)(mbase + nb);
        mp0 = q[0]; mp1 = q[1];
        i4 w0, w1;
        w0.x = (int)pack2bf(a0.x, a0.y); w0.y = (int)pack2bf(a0.z, a0.w);
        w0.z = (int)pack2bf(a1.x, a1.y); w0.w = (int)pack2bf(a1.z, a1.w);
        w1.x = (int)pack2bf(a2.x, a2.y); w1.y = (int)pack2bf(a2.z, a2.w);
        w1.z = (int)pack2bf(a3.x, a3.y); w1.w = (int)pack2bf(a3.z, a3.w);
        *(i4*)(As0 + aw0) = w0;
        *(i4*)(As0 + aw1) = w1;
        *(i4*)(Ms0 + mwoff) = mask2bf(mp0, mp1);
        if (NC > 1) {
            const f4* p1 = (const f4*)(abase + (size_t)(nb + 32) * 256);
            a0 = p1[0]; a1 = p1[1]; a2 = p1[2]; a3 = p1[3];
            const i4* q1 = (const i4*)(mbase + nb + 32);
            mp0 = q1[0]; mp1 = q1[1];
        }
    }
    bar_lgkm();

    int cur = 0;
    for (int c = 0; c < NC; ++c) {
        const char* Ar = As0 + cur * 16384;
        // ---- B+C: h-MFMA + fused sigmoid epilogue, dt-sequential (h acc = 16 regs) ----
        {   // dt = 0
            acc4 t0 = (acc4)0.f, t1 = (acc4)0.f, ga = (acc4)0.f, gb = (acc4)0.f;
#pragma unroll
            for (int ks = 0; ks < 8; ++ks) {
                const int gg = ks * 4 + quad;
                const int ab = gg * 512 + (((l16 & 8) | ((l16 ^ gg) & 7)) << 4);
                s8 af0 = *(const s8*)(Ar + ab);
                s8 af1 = *(const s8*)(Ar + ab + 256);
                t0 = __builtin_amdgcn_mfma_f32_16x16x32_bf16(af0, wT0[ks], t0, 0, 0, 0);
                ga = __builtin_amdgcn_mfma_f32_16x16x32_bf16(af0, wG0[ks], ga, 0, 0, 0);
                t1 = __builtin_amdgcn_mfma_f32_16x16x32_bf16(af1, wT0[ks], t1, 0, 0, 0);
                gb = __builtin_amdgcn_mfma_f32_16x16x32_bf16(af1, wG0[ks], gb, 0, 0, 0);
            }
#pragma unroll
            for (int nt = 0; nt < 2; ++nt) {
                const acc4 t = nt ? t1 : t0;
                const acc4 g = nt ? gb : ga;
                float h0 = (t[0] + bt0) / (1.0f + __expf(-(g[0] + bg0)));
                float h1 = (t[1] + bt0) / (1.0f + __expf(-(g[1] + bg0)));
                float h2 = (t[2] + bt0) / (1.0f + __expf(-(g[2] + bg0)));
                float h3 = (t[3] + bt0) / (1.0f + __expf(-(g[3] + bg0)));
                u2 pk; pk.x = pack2bf(h0, h1); pk.y = pack2bf(h2, h3);
                const int gn = nt * 2 + (quad >> 1);
                *(u2*)(Hs + d0 * 64 + ((gn ^ (d0 & 3)) << 4) + (quad & 1) * 8) = pk;
            }
        }
        {   // dt = 1
            acc4 t0 = (acc4)0.f, t1 = (acc4)0.f, ga = (acc4)0.f, gb = (acc4)0.f;
#pragma unroll
            for (int ks = 0; ks < 8; ++ks) {
                const int gg = ks * 4 + quad;
                const int ab = gg * 512 + (((l16 & 8) | ((l16 ^ gg) & 7)) << 4);
                s8 af0 = *(const s8*)(Ar + ab);
                s8 af1 = *(const s8*)(Ar + ab + 256);
                t0 = __builtin_amdgcn_mfma_f32_16x16x32_bf16(af0, wT1[ks], t0, 0, 0, 0);
                ga = __builtin_amdgcn_mfma_f32_16x16x32_bf16(af0, wG1[ks], ga, 0, 0, 0);
                t1 = __builtin_amdgcn_mfma_f32_16x16x32_bf16(af1, wT1[ks], t1, 0, 0, 0);
                gb = __builtin_amdgcn_mfma_f32_16x16x32_bf16(af1, wG1[ks], gb, 0, 0, 0);
            }
#pragma unroll
            for (int nt = 0; nt < 2; ++nt) {
                const acc4 t = nt ? t1 : t0;
                const acc4 g = nt ? gb : ga;
                float h0 = (t[0] + bt1) / (1.0f + __expf(-(g[0] + bg1)));
                float h1 = (t[1] + bt1) / (1.0f + __expf(-(g[1] + bg1)));
                float h2 = (t[2] + bt1) / (1.0f + __expf(-(g[2] + bg1)));
                float h3 = (t[3] + bt1) / (1.0f + __expf(-(g[3] + bg1)));
                u2 pk; pk.x = pack2bf(h0, h1); pk.y = pack2bf(h2, h3);
                const int gn = nt * 2 + (quad >> 1);
                *(u2*)(Hs + d1 * 64 + ((gn ^ (d1 & 3)) << 4) + (quad & 1) * 8) = pk;
            }
        }
        // ---- D: stage chunk c+1 (regs, loaded a chunk ago; compiler waits vmcnt here) ----
        if (c + 1 < NC) {
            char* Aw = As0 + (cur ^ 1) * 16384;
            i4 w0, w1;
            w0.x = (int)pack2bf(a0.x, a0.y); w0.y = (int)pack2bf(a0.z, a0.w);
            w0.z = (int)pack2bf(a1.x, a1.y); w0.w = (int)pack2bf(a1.z, a1.w);
            w1.x = (int)pack2bf(a2.x, a2.y); w1.y = (int)pack2bf(a2.z, a2.w);
            w1.z = (int)pack2bf(a3.x, a3.y); w1.w = (int)pack2bf(a3.z, a3.w);
            *(i4*)(Aw + aw0) = w0;
            *(i4*)(Aw + aw1) = w1;
            *(i4*)(Ms0 + (cur ^ 1) * 8192 + mwoff) = mask2bf(mp0, mp1);
        }
        // ---- E: issue chunk c+2 loads (stay in flight across lgkm-only barriers) ----
        if (c + 2 < NC) {
            const int nb2 = (ch0 + c + 2) * 32;
            const f4* p = (const f4*)(abase + (size_t)nb2 * 256);
            a0 = p[0]; a1 = p[1]; a2 = p[2]; a3 = p[3];
            const i4* q = (const i4*)(mbase + nb2);
            mp0 = q[0]; mp1 = q[1];
        }
        bar_lgkm();   // F: Hs + As/Ms[cur^1] visible
        // ---- G: res-MFMA: 128b x 256d x K=32 (16 MFMA/wave) ----
        {
            const char* Mr = Ms0 + cur * 8192;
            s8 maf[4];
#pragma unroll
            for (int rt = 0; rt < 4; ++rt) {
                const int r = bh * 64 + rt * 16 + l16;
                maf[rt] = *(const s8*)(Mr + r * 64 + ((quad ^ (r & 3)) << 4));
            }
#pragma unroll
            for (int dt = 0; dt < 4; ++dt) {
                const int dl = dq * 64 + dt * 16 + l16;
                s8 hb = *(const s8*)(Hs + dl * 64 + ((quad ^ (dl & 3)) << 4));
#pragma unroll
                for (int rt = 0; rt < 4; ++rt)
                    acc[rt][dt] = __builtin_amdgcn_mfma_f32_16x16x32_bf16(maf[rt], hb, acc[rt][dt], 0, 0, 0);
            }
        }
        bar_lgkm();   // H: res reads of Hs/Ms[cur] done
        cur ^= 1;
    }
    // ---- epilogue: f32 partial store ----
    float* pb = partials + (((size_t)half * 256 + xr) << 15);
#pragma unroll
    for (int rt = 0; rt < 4; ++rt)
#pragma unroll
        for (int dt = 0; dt < 4; ++dt) {
            const int b = bh * 64 + rt * 16 + quad * 4;
            const int d = dq * 64 + dt * 16 + l16;
#pragma unroll
            for (int r = 0; r < 4; ++r)
                pb[(size_t)(b + r) * 256 + d] = acc[rt][dt][r];
        }
}

// ---------------- reduce: out[b][d] = sum_xr partials[b>>7][xr][b&127][d] ----------------
__global__ __launch_bounds__(1024) void k_red(const float* __restrict__ partials,
                                              float* __restrict__ outp) {
    __shared__ float red[4][256];
    const int b = blockIdx.x;
    const int d = threadIdx.x & 255, ks = threadIdx.x >> 8;
    const int half = b >> 7, lb = b & 127;
    const float* p = partials + (((size_t)half * 256 + ks * 64) << 15) + lb * 256 + d;
    float s0 = 0.f, s1 = 0.f, s2 = 0.f, s3 = 0.f;
#pragma unroll 4
    for (int j = 0; j < 64; j += 4) {
        s0 += p[(size_t)(j + 0) << 15];
        s1 += p[(size_t)(j + 1) << 15];
        s2 += p[(size_t)(j + 2) << 15];
        s3 += p[(size_t)(j + 3) << 15];
    }
    red[ks][d] = (s0 + s1) + (s2 + s3);
    __syncthreads();
    if (ks == 0)
        outp[b * 256 + d] = (red[0][d] + red[1][d]) + (red[2][d] + red[3][d]);
}

extern "C" void kernel_launch(void* const* d_in, const int* in_sizes, int n_in,
                              void* d_out, int out_size, void* d_ws, size_t ws_size,
                              hipStream_t stream) {
    const float* nodes = (const float*)d_in[0];
    const int*   masks = (const int*)d_in[1];
    const float* Wt    = (const float*)d_in[2];
    const float* bt    = (const float*)d_in[3];
    const float* Wg    = (const float*)d_in[4];
    const float* bg    = (const float*)d_in[5];
    float* outp = (float*)d_out;

    // ws layout: wtb/wgb bf16 (131,072 B); partials f32 [2][256][128][256] = 67,108,864 B
    u16*   wtb  = (u16*)d_ws;
    u16*   wgb  = wtb + 65536;
    float* part = (float*)((char*)d_ws + 262144);

    k_prep<<<dim3(256), dim3(256), 0, stream>>>(Wt, Wg, wtb, wgb);
    k_main<<<dim3(2, 256), dim3(512), 0, stream>>>(nodes, masks, wtb, wgb, bt, bg, part);
    k_red<<<dim3(256), dim3(1024), 0, stream>>>(part, outp);
}